// Round 15
// baseline (693.827 us; speedup 1.0000x reference)
//
#include <hip/hip_runtime.h>
#include <hip/hip_bf16.h>
#include <cstdint>
#include <cstddef>

#define DEV __device__ __forceinline__

typedef float f32x4 __attribute__((ext_vector_type(4)));
typedef short s16x8 __attribute__((ext_vector_type(8)));
typedef short s16x4 __attribute__((ext_vector_type(4)));
typedef __bf16 bf16x8 __attribute__((ext_vector_type(8)));

DEV unsigned short f2bf(float f) {
  union { float f; unsigned u; } v; v.f = f;
  return (unsigned short)((v.u + 0x7FFFu + ((v.u >> 16) & 1u)) >> 16);
}
DEV float bf2f(unsigned short s) {
  union { unsigned u; float f; } v; v.u = ((unsigned)s) << 16;
  return v.f;
}

DEV void mfma16(f32x4& d, const s16x8& a, const s16x8& b) {
  d = __builtin_amdgcn_mfma_f32_16x16x32_bf16(
      __builtin_bit_cast(bf16x8, a), __builtin_bit_cast(bf16x8, b), d, 0, 0, 0);
}

typedef const unsigned int gu32 __attribute__((address_space(1)));
typedef unsigned int lu32 __attribute__((address_space(3)));
DEV void gl_lds16(const void* g, void* l) {
  __builtin_amdgcn_global_load_lds((gu32*)g, (lu32*)l, 16, 0, 0);
}

// ---------------------------------------------------------------------------
// Zero-filling tile transpose: fp32 (Ksrc x nColsSrc submatrix) -> bf16.
// Reads outside the source range yield 0; writes are UNCONDITIONAL (caller
// guarantees the dst tile is in-range). ilv=1: dstRow = (n/16)*32+(n%16)+rowOff.
// ---------------------------------------------------------------------------
DEV void transpose_tile(const float* __restrict__ src, int srcLd, int Ksrc,
                        int colOff, int nColsSrc,
                        unsigned short* __restrict__ dst, int dstLd, int rowOff,
                        int ilv, int bx, int by, int tid)
{
  __shared__ float tile[32][33];
  int tx = tid & 31, ty = tid >> 5;
  int k0 = by * 32, n0 = bx * 32;
#pragma unroll
  for (int r = 0; r < 4; ++r) {
    int kk = k0 + ty + r * 8;
    int nn = n0 + tx;
    float v = 0.f;
    if (kk < Ksrc && nn < nColsSrc) v = src[(size_t)kk * srcLd + colOff + nn];
    tile[ty + r * 8][tx] = v;
  }
  __syncthreads();
#pragma unroll
  for (int r = 0; r < 4; ++r) {
    int nn = n0 + ty + r * 8;
    int kk = k0 + tx;
    int row = ilv ? (((nn >> 4) << 5) + (nn & 15) + rowOff) : (rowOff + nn);
    dst[(size_t)row * dstLd + kk] = f2bf(tile[tx][ty + r * 8]);
  }
}

// ---------------------------------------------------------------------------
// prep_all: 5 weight transposes (pad-writing, no memset needed) + w12 biasPad
// + ada GEMV, all in ONE dispatch (12662 blocks).
// ---------------------------------------------------------------------------
__global__ void prep_all(const float* __restrict__ qkvW, unsigned short* __restrict__ qkvT,
                         const float* __restrict__ outW, unsigned short* __restrict__ outT,
                         const float* __restrict__ w12W, unsigned short* __restrict__ w12T,
                         const float* __restrict__ w3W,  unsigned short* __restrict__ w3T,
                         const float* __restrict__ w12B, float* __restrict__ biasPad,
                         const float* __restrict__ c, const float* __restrict__ adaW,
                         const float* __restrict__ adaB, float* __restrict__ ada)
{
  const int id = blockIdx.x;
  const int tid = threadIdx.x;
  if (id < 3072) {
    transpose_tile(qkvW, 3072, 1024, 0, 3072, qkvT, 1024, 0, 0, id % 96, id / 96, tid);
  } else if (id < 4096) {
    int t = id - 3072;
    transpose_tile(outW, 1024, 1024, 0, 1024, outT, 1024, 0, 0, t % 32, t / 32, tid);
  } else if (id < 6912) {
    int t = id - 4096;
    transpose_tile(w12W, 5460, 1024, 0, 2730, w12T, 1024, 0, 1, t % 88, t / 88, tid);
  } else if (id < 9728) {
    int t = id - 6912;
    transpose_tile(w12W, 5460, 1024, 2730, 2730, w12T, 1024, 16, 1, t % 88, t / 88, tid);
  } else if (id < 12544) {
    int t = id - 9728;
    transpose_tile(w3W, 1024, 2730, 0, 1024, w3T, 2816, 0, 0, t % 32, t / 32, tid);
  } else if (id < 12566) {
    int n = (id - 12544) * 256 + tid;
    if (n < 5632) {
      int bb = n >> 4, i = n & 15;
      int src = ((bb >> 1) << 4) + i;
      float v = 0.f;
      if (src < 2730) v = (bb & 1) ? w12B[2730 + src] : w12B[src];
      biasPad[n] = v;
    }
  } else {
    __shared__ float cs[1024];
    int t = id - 12566;
    int bb = t / 24;
    int j = (t % 24) * 256 + tid;
    for (int i = tid; i < 1024; i += 256) {
      float v = c[bb * 1024 + i];
      cs[i] = v / (1.f + __expf(-v));
    }
    __syncthreads();
    float acc = adaB[j];
    for (int k = 0; k < 1024; ++k) acc = fmaf(cs[k], adaW[(size_t)k * 6144 + j], acc);
    ada[bb * 6144 + j] = acc;
  }
}

// ---------------------------------------------------------------------------
// rmsmod: wave-per-row (64 lanes x 16 f32), 4 rows/block, no LDS.
// ---------------------------------------------------------------------------
__global__ void rmsmod_kernel(const float* __restrict__ x, const float* __restrict__ nsc,
                              const float* __restrict__ ada, int shOff, int scOff,
                              unsigned short* __restrict__ out)
{
  const int lane = threadIdx.x & 63;
  const int wv = threadIdx.x >> 6;
  const int row = blockIdx.x * 4 + wv;
  const f32x4* xr = (const f32x4*)(x + (size_t)row * 1024);
  f32x4 v[4];
  float ss = 0.f;
#pragma unroll
  for (int c = 0; c < 4; ++c) {
    v[c] = xr[c * 64 + lane];
    ss += v[c][0]*v[c][0] + v[c][1]*v[c][1] + v[c][2]*v[c][2] + v[c][3]*v[c][3];
  }
#pragma unroll
  for (int off = 32; off >= 1; off >>= 1) ss += __shfl_xor(ss, off, 64);
  const float rms = rsqrtf(ss * (1.f / 1024.f) + 1e-6f);
  const int bb = row >> 12;
  const float* ab = ada + bb * 6144;
#pragma unroll
  for (int c = 0; c < 4; ++c) {
    s16x4 o;
#pragma unroll
    for (int i = 0; i < 4; ++i) {
      int col = (c * 64 + lane) * 4 + i;
      float xn = v[c][i] * rms * nsc[col];
      float val = xn * (1.f + ab[scOff + col]) + ab[shOff + col];
      o[i] = (short)f2bf(val);
    }
    *(s16x4*)(out + (size_t)row * 1024 + (c * 64 + lane) * 4) = o;
  }
}

// ---------------------------------------------------------------------------
// gemm256: C = A(bf16 MxK, lda) * BT(bf16 NxK, ldb)^T + bias.
// 256x256 tile, BK=64, 8 waves (2Mx4N), mfma_16x16x32. R5 2-barrier K-loop.
// EPI 1: silu-pair (16-interleaved w12) -> Nout=N/2
// EPI 2: f32 res + gate*(v+b)   (full-M only: gate row = rg>>12)
// EPI 3: qkv with fused V-transpose (cols>=2048 scatter to vT layout)
// Requires M%256==0, N%256==0, K%64==0, K/64>=2, grid%8==0.
// ---------------------------------------------------------------------------
template<int EPI>
__global__ __launch_bounds__(512, 2) void gemm256(
    const unsigned short* __restrict__ A, int lda,
    const unsigned short* __restrict__ BT, int ldb,
    int N, int K,
    const float* __restrict__ bias,
    void* __restrict__ Cout, int Nout,
    const float* __restrict__ res,
    const float* __restrict__ ada, int gateOff,
    unsigned short* __restrict__ vTout)
{
  __shared__ __align__(16) char lds[131072];

  const int tid = threadIdx.x;
  const int lane = tid & 63;
  const int wv = tid >> 6;
  const int wr = wv >> 2;        // 0..1  (M half)
  const int wn = wv & 3;         // 0..3  (N quarter)
  const int g = lane >> 4, r16 = lane & 15;

  // XCD-aware bijective block swizzle (grid % 8 == 0)
  const int nwg = gridDim.x * gridDim.y;
  const int bid = blockIdx.x + gridDim.x * blockIdx.y;
  const int qq = nwg >> 3;
  const int swz = (bid & 7) * qq + (bid >> 3);
  const int m0 = (swz / gridDim.x) * 256;
  const int n0 = (swz % gridDim.x) * 256;

  const int nkt = K >> 6;

  auto stageB = [&](int t) {
    if (t >= nkt) return;
    const int bs = t & 1;
#pragma unroll
    for (int it = 0; it < 4; ++it) {
      const int cidx = it * 512 + tid;
      const int rl = cidx >> 3, cc = cidx & 7;
      const unsigned short* src =
          BT + (size_t)(n0 + rl) * ldb + t * 64 + ((cc ^ (rl & 7)) << 3);
      gl_lds16(src, lds + 65536 + bs * 32768 + cidx * 16);
    }
  };
  auto stageA = [&](int t) {
    if (t >= nkt) return;
    const int bs = t & 1;
#pragma unroll
    for (int it = 0; it < 4; ++it) {
      const int cidx = it * 512 + tid;
      const int rl = cidx >> 3, cc = cidx & 7;
      const unsigned short* src =
          A + (size_t)(m0 + rl) * lda + t * 64 + ((cc ^ (rl & 7)) << 3);
      gl_lds16(src, lds + bs * 32768 + cidx * 16);
    }
  };

  f32x4 acc[8][4];
#pragma unroll
  for (int m = 0; m < 8; ++m)
#pragma unroll
    for (int n = 0; n < 4; ++n) { acc[m][n][0]=0.f; acc[m][n][1]=0.f; acc[m][n][2]=0.f; acc[m][n][3]=0.f; }

  int swzk[2];
#pragma unroll
  for (int ks = 0; ks < 2; ++ks) swzk[ks] = (((ks << 2) + g) ^ (r16 & 7)) << 4;
  int arow0[4], arow1[4], brow0[2], brow1[2];
#pragma unroll
  for (int m = 0; m < 4; ++m) {
    arow0[m] = (wr * 128 + m * 16 + r16) * 128;
    arow1[m] = (wr * 128 + 64 + m * 16 + r16) * 128;
  }
#pragma unroll
  for (int n = 0; n < 2; ++n) {
    brow0[n] = 65536 + (wn * 64 + n * 16 + r16) * 128;
    brow1[n] = 65536 + (wn * 64 + 32 + n * 16 + r16) * 128;
  }

  // prologue: tiles 0,1 staged; vmcnt(8) -> tile 0 landed
  stageB(0); stageA(0); stageB(1); stageA(1);
  asm volatile("s_waitcnt vmcnt(8)" ::: "memory");
  __builtin_amdgcn_s_barrier();

  for (int kt = 0; kt < nkt; ++kt) {
    const int boff = (kt & 1) * 32768;
    s16x8 a0[4][2], a1[4][2], b0[2][2], b1[2][2];
#pragma unroll
    for (int m = 0; m < 4; ++m)
#pragma unroll
      for (int ks = 0; ks < 2; ++ks)
        a0[m][ks] = *(const s16x8*)(lds + boff + arow0[m] + swzk[ks]);
#pragma unroll
    for (int n = 0; n < 2; ++n)
#pragma unroll
      for (int ks = 0; ks < 2; ++ks)
        b0[n][ks] = *(const s16x8*)(lds + boff + brow0[n] + swzk[ks]);
#pragma unroll
    for (int n = 0; n < 2; ++n)
#pragma unroll
      for (int ks = 0; ks < 2; ++ks)
        b1[n][ks] = *(const s16x8*)(lds + boff + brow1[n] + swzk[ks]);
#pragma unroll
    for (int m = 0; m < 4; ++m)
#pragma unroll
      for (int ks = 0; ks < 2; ++ks)
        a1[m][ks] = *(const s16x8*)(lds + boff + arow1[m] + swzk[ks]);
    // ---- Q00 ----
    __builtin_amdgcn_s_setprio(1);
#pragma unroll
    for (int m = 0; m < 4; ++m)
#pragma unroll
      for (int n = 0; n < 2; ++n)
#pragma unroll
        for (int ks = 0; ks < 2; ++ks)
          mfma16(acc[m][n], a0[m][ks], b0[n][ks]);
    __builtin_amdgcn_s_setprio(0);
    // ---- Q01 ----
    __builtin_amdgcn_s_setprio(1);
#pragma unroll
    for (int m = 0; m < 4; ++m)
#pragma unroll
      for (int n = 0; n < 2; ++n)
#pragma unroll
        for (int ks = 0; ks < 2; ++ks)
          mfma16(acc[m][2 + n], a0[m][ks], b1[n][ks]);
    __builtin_amdgcn_s_setprio(0);
    __builtin_amdgcn_s_barrier();          // BAR-mid: all B/a0 reads drained
    // ---- stage B(kt+2), Q11 ----
    stageB(kt + 2);
    __builtin_amdgcn_s_setprio(1);
#pragma unroll
    for (int m = 0; m < 4; ++m)
#pragma unroll
      for (int n = 0; n < 2; ++n)
#pragma unroll
        for (int ks = 0; ks < 2; ++ks)
          mfma16(acc[4 + m][2 + n], a1[m][ks], b1[n][ks]);
    __builtin_amdgcn_s_setprio(0);
    if (kt + 2 < nkt) asm volatile("s_waitcnt vmcnt(4)" ::: "memory");
    else              asm volatile("s_waitcnt vmcnt(0)" ::: "memory");
    __builtin_amdgcn_s_barrier();          // BAR-late: A drained + kt+1 landed
    // ---- stage A(kt+2), Q10 ----
    stageA(kt + 2);
    __builtin_amdgcn_s_setprio(1);
#pragma unroll
    for (int m = 0; m < 4; ++m)
#pragma unroll
      for (int n = 0; n < 2; ++n)
#pragma unroll
        for (int ks = 0; ks < 2; ++ks)
          mfma16(acc[4 + m][n], a1[m][ks], b0[n][ks]);
    __builtin_amdgcn_s_setprio(0);
  }

  if (EPI == 1) {
    unsigned short* Co = (unsigned short*)Cout;
#pragma unroll
    for (int fm = 0; fm < 8; ++fm)
#pragma unroll
      for (int p = 0; p < 2; ++p)
#pragma unroll
        for (int r = 0; r < 4; ++r) {
          int rg = m0 + wr * 128 + fm * 16 + g * 4 + r;
          int cg = n0 + wn * 64 + (2 * p) * 16 + r16;
          float v1 = acc[fm][2 * p][r] + bias[cg];
          float v2 = acc[fm][2 * p + 1][r] + bias[cg + 16];
          float h = v1 / (1.f + __expf(-v1)) * v2;
          int hcol = (n0 >> 1) + wn * 32 + p * 16 + r16;
          Co[(size_t)rg * Nout + hcol] = f2bf(h);
        }
  } else if (EPI == 2) {
    float* Co = (float*)Cout;
#pragma unroll
    for (int fm = 0; fm < 8; ++fm)
#pragma unroll
      for (int fn = 0; fn < 4; ++fn)
#pragma unroll
        for (int r = 0; r < 4; ++r) {
          int rg = m0 + wr * 128 + fm * 16 + g * 4 + r;
          int cg = n0 + wn * 64 + fn * 16 + r16;
          float v = acc[fm][fn][r] + bias[cg];
          int bb = rg >> 12;
          float gate = ada[bb * 6144 + gateOff + cg];
          size_t idx = (size_t)rg * Nout + cg;
          Co[idx] = res[idx] + gate * v;
        }
  } else { // EPI == 3: qkv; V-part (cols>=2048) scattered into vT layout
    unsigned short* Co = (unsigned short*)Cout;
#pragma unroll
    for (int fn = 0; fn < 4; ++fn) {
      int cg = n0 + wn * 64 + fn * 16 + r16;
      float bs = bias[cg];
      if (n0 + wn * 64 + fn * 16 < 2048) {
#pragma unroll
        for (int fm = 0; fm < 8; ++fm)
#pragma unroll
          for (int r = 0; r < 4; ++r) {
            int rg = m0 + wr * 128 + fm * 16 + g * 4 + r;
            Co[(size_t)rg * Nout + cg] = f2bf(acc[fm][fn][r] + bs);
          }
      } else {
        int h = (cg - 2048) >> 6, d = (cg - 2048) & 63;
        unsigned short* vcol = vTout + (size_t)h * 16384 + d * 256;
#pragma unroll
        for (int fm = 0; fm < 8; ++fm)
#pragma unroll
          for (int r = 0; r < 4; ++r) {
            int rg = m0 + wr * 128 + fm * 16 + g * 4 + r;
            vcol[((size_t)(rg >> 8) * 16) * 16384 + (rg & 255)] =
                f2bf(acc[fm][fn][r] + bs);
          }
      }
    }
  }
}

// ---------------------------------------------------------------------------
// GEMM 128x128 (2-barrier structure) for the chunked-fallback out-proj.
// ---------------------------------------------------------------------------
template<int MODE>
__global__ void gemm128(const unsigned short* __restrict__ A, int lda,
                        const unsigned short* __restrict__ BT,
                        int N, int K,
                        const float* __restrict__ bias,
                        void* __restrict__ Cout,
                        const float* __restrict__ res,
                        const float* __restrict__ ada, int gateOff, int mOff)
{
  __shared__ __align__(16) unsigned short As[128 * 32];
  __shared__ __align__(16) unsigned short Bs[128 * 32];

  const int tid = threadIdx.x;
  const int lane = tid & 63;
  const int wv = tid >> 6;
  const int wr = wv >> 1, wc = wv & 1;
  const int g = lane >> 4, r16 = lane & 15;
  const int m0 = blockIdx.y * 128, n0 = blockIdx.x * 128;

  const int c0 = tid, c1 = 256 + tid;
  const int ra0 = c0 >> 2, ra1 = c1 >> 2;
  const int k0 = ((c0 & 3) ^ ((ra0 >> 1) & 3)) * 8;
  const int k1 = ((c1 & 3) ^ ((ra1 >> 1) & 3)) * 8;
  const unsigned short* ga0 = A + (size_t)(m0 + ra0) * lda + k0;
  const unsigned short* ga1 = A + (size_t)(m0 + ra1) * lda + k1;
  const unsigned short* gb0 = BT + (size_t)(n0 + ra0) * K + k0;
  const unsigned short* gb1 = BT + (size_t)(n0 + ra1) * K + k1;
  unsigned short* la0 = As + c0 * 8;
  unsigned short* la1 = As + c1 * 8;
  unsigned short* lb0 = Bs + c0 * 8;
  unsigned short* lb1 = Bs + c1 * 8;

  f32x4 acc[4][4];
#pragma unroll
  for (int m = 0; m < 4; ++m)
#pragma unroll
    for (int n = 0; n < 4; ++n) { acc[m][n][0]=0.f; acc[m][n][1]=0.f; acc[m][n][2]=0.f; acc[m][n][3]=0.f; }

  int aoff[4], boff[4];
#pragma unroll
  for (int m = 0; m < 4; ++m) {
    int rl = wr * 64 + m * 16 + r16;
    aoff[m] = rl * 32 + (g ^ ((rl >> 1) & 3)) * 8;
    int rb = wc * 64 + m * 16 + r16;
    boff[m] = rb * 32 + (g ^ ((rb >> 1) & 3)) * 8;
  }

  const int nk = K >> 5;
  for (int kt = 0; kt < nk; ++kt) {
    __syncthreads();
    const int ko = kt * 32;
    gl_lds16(ga0 + ko, la0);
    gl_lds16(ga1 + ko, la1);
    gl_lds16(gb0 + ko, lb0);
    gl_lds16(gb1 + ko, lb1);
    __syncthreads();
    s16x8 af[4], bf[4];
#pragma unroll
    for (int m = 0; m < 4; ++m) af[m] = *(const s16x8*)(As + aoff[m]);
#pragma unroll
    for (int n = 0; n < 4; ++n) bf[n] = *(const s16x8*)(Bs + boff[n]);
#pragma unroll
    for (int m = 0; m < 4; ++m)
#pragma unroll
      for (int n = 0; n < 4; ++n) mfma16(acc[m][n], af[m], bf[n]);
  }

#pragma unroll
  for (int m = 0; m < 4; ++m) {
#pragma unroll
    for (int n = 0; n < 4; ++n) {
#pragma unroll
      for (int r = 0; r < 4; ++r) {
        int rg = m0 + wr * 64 + m * 16 + g * 4 + r;
        int cg = n0 + wc * 64 + n * 16 + r16;
        float v = acc[m][n][r] + bias[cg];
        size_t idx = (size_t)rg * N + cg;
        if (MODE == 0 || MODE == 2) {
          ((unsigned short*)Cout)[idx] = f2bf(v);
        } else {
          int bb = (mOff + rg) >> 12;
          float gate = ada[bb * 6144 + gateOff + cg];
          ((float*)Cout)[idx] = res[idx] + gate * v;
        }
      }
    }
  }
}

// ---------------------------------------------------------------------------
// Fused windowed attention. LDS diet: V read DIRECTLY from global (vT is
// block-unique, read once per wave -> staging was pure overhead; m169).
// LDS = Kl 32KB + Pl 44KB = 76KB <= 80KB -> 2 blocks/CU.
// ---------------------------------------------------------------------------
__global__ __launch_bounds__(256) void attn_kernel(
    const unsigned short* __restrict__ qkv,
    const unsigned short* __restrict__ vT,
    unsigned short* __restrict__ attnout)
{
  __shared__ __align__(16) unsigned short Kl[256 * 64];
  __shared__ __align__(16) unsigned short Pl[4][64 * 88];

  const int tid = threadIdx.x;
  const int lane = tid & 63;
  const int wv = tid >> 6;
  const int g = lane >> 4, r16 = lane & 15;
  const int p = blockIdx.x;
  const int w = p >> 4, h = p & 15;
  const float hh = (float)h;
  const float F = 0.4152410118609203f; // log2(10000)/32

#pragma unroll
  for (int it = 0; it < 4; ++it) {
    int idx = it * 256 + tid;
    int j = idx >> 2;
    int c = idx & 3;
    const unsigned short* kg = qkv + (size_t)(w * 256 + j) * 3072 + 1024 + h * 64;
    s16x8 lo = *(const s16x8*)(kg + c * 8);
    s16x8 hi = *(const s16x8*)(kg + 32 + c * 8);
    s16x8 plo, phi;
#pragma unroll
    for (int i2 = 0; i2 < 4; ++i2) {
      float f1 = exp2f(-(float)(c * 4 + i2) * F);
      float f2 = exp2f(-(float)(16 + c * 4 + i2) * F);
      float s1, c1s, s2, c2s;
      sincosf(hh * f1, &s1, &c1s);
      sincosf(hh * f2, &s2, &c2s);
#pragma unroll
      for (int u = 0; u < 2; ++u) {
        int i = i2 * 2 + u;
        float a = bf2f((unsigned short)lo[i]);
        float b = bf2f((unsigned short)hi[i]);
        plo[i] = (short)f2bf(a * c1s - b * s1);
        phi[i] = (short)f2bf(b * c2s + a * s2);
      }
    }
    int swzL = c ^ (j & 7);
    int swzH = (c + 4) ^ (j & 7);
    *(s16x8*)(Kl + j * 64 + swzL * 8) = plo;
    *(s16x8*)(Kl + j * 64 + swzH * 8) = phi;
  }

  s16x8 qa[4][2];
  {
    float cs0[4], sn0[4], cs1[4], sn1[4];
#pragma unroll
    for (int i2 = 0; i2 < 4; ++i2) {
      float f1 = exp2f(-(float)(g * 4 + i2) * F);
      float f2 = exp2f(-(float)(16 + g * 4 + i2) * F);
      sincosf(hh * f1, &sn0[i2], &cs0[i2]);
      sincosf(hh * f2, &sn1[i2], &cs1[i2]);
    }
#pragma unroll
    for (int m = 0; m < 4; ++m) {
      const unsigned short* qg =
          qkv + (size_t)(w * 256 + wv * 64 + m * 16 + r16) * 3072 + h * 64;
      s16x8 lo = *(const s16x8*)(qg + g * 8);
      s16x8 hi = *(const s16x8*)(qg + 32 + g * 8);
      s16x8 plo, phi;
#pragma unroll
      for (int i = 0; i < 8; ++i) {
        int i2 = i >> 1;
        float a = bf2f((unsigned short)lo[i]);
        float b = bf2f((unsigned short)hi[i]);
        plo[i] = (short)f2bf(a * cs0[i2] - b * sn0[i2]);
        phi[i] = (short)f2bf(b * cs1[i2] + a * sn1[i2]);
      }
      qa[m][0] = plo;
      qa[m][1] = phi;
    }
  }

  __syncthreads();

  const unsigned short* vg = vT + (size_t)p * (64 * 256);

  f32x4 accO[4][4];
  float Mx[4][4], Ls[4][4];
#pragma unroll
  for (int m = 0; m < 4; ++m)
#pragma unroll
    for (int r = 0; r < 4; ++r) {
      Mx[m][r] = -3.0e38f;
      Ls[m][r] = 0.f;
      accO[m][r][0]=0.f; accO[m][r][1]=0.f; accO[m][r][2]=0.f; accO[m][r][3]=0.f;
    }
  unsigned short* Pw = &Pl[wv][0];
  const float zs = 0.125f * 1.44269504f;

  for (int kb = 0; kb < 4; ++kb) {
    f32x4 s[4][4];
#pragma unroll
    for (int m = 0; m < 4; ++m)
#pragma unroll
      for (int jt = 0; jt < 4; ++jt) { s[m][jt][0]=0.f; s[m][jt][1]=0.f; s[m][jt][2]=0.f; s[m][jt][3]=0.f; }

#pragma unroll
    for (int jt = 0; jt < 4; ++jt) {
      int j = kb * 64 + jt * 16 + r16;
      s16x8 bk0 = *(const s16x8*)(Kl + j * 64 + ((g ^ (j & 7)) * 8));
      s16x8 bk1 = *(const s16x8*)(Kl + j * 64 + (((4 + g) ^ (j & 7)) * 8));
#pragma unroll
      for (int m = 0; m < 4; ++m) {
        mfma16(s[m][jt], qa[m][0], bk0);
        mfma16(s[m][jt], qa[m][1], bk1);
      }
    }

#pragma unroll
    for (int m = 0; m < 4; ++m) {
#pragma unroll
      for (int r = 0; r < 4; ++r) {
        float mx = fmaxf(fmaxf(s[m][0][r], s[m][1][r]), fmaxf(s[m][2][r], s[m][3][r]));
        mx = fmaxf(mx, __shfl_xor(mx, 1, 16));
        mx = fmaxf(mx, __shfl_xor(mx, 2, 16));
        mx = fmaxf(mx, __shfl_xor(mx, 4, 16));
        mx = fmaxf(mx, __shfl_xor(mx, 8, 16));
        float Mn = fmaxf(Mx[m][r], mx * zs);
        float fsc = exp2f(Mx[m][r] - Mn);
        Mx[m][r] = Mn;
        float ps = 0.f;
#pragma unroll
        for (int jt = 0; jt < 4; ++jt) {
          float pv = exp2f(s[m][jt][r] * zs - Mn);
          s[m][jt][r] = pv;
          ps += pv;
        }
        ps += __shfl_xor(ps, 1, 16);
        ps += __shfl_xor(ps, 2, 16);
        ps += __shfl_xor(ps, 4, 16);
        ps += __shfl_xor(ps, 8, 16);
        Ls[m][r] = Ls[m][r] * fsc + ps;
#pragma unroll
        for (int dt = 0; dt < 4; ++dt) accO[m][dt][r] *= fsc;
      }
    }

#pragma unroll
    for (int m = 0; m < 4; ++m)
#pragma unroll
      for (int jt = 0; jt < 4; ++jt)
#pragma unroll
        for (int r = 0; r < 4; ++r) {
          int q = m * 16 + g * 4 + r;
          int jj = jt * 16 + r16;
          Pw[q * 88 + jj] = f2bf(s[m][jt][r]);
        }
    asm volatile("s_waitcnt lgkmcnt(0)" ::: "memory");
    __builtin_amdgcn_sched_barrier(0);

#pragma unroll
    for (int c = 0; c < 2; ++c) {
      s16x8 pa[4];
#pragma unroll
      for (int m = 0; m < 4; ++m)
        pa[m] = *(const s16x8*)(Pw + (m * 16 + r16) * 88 + c * 32 + g * 8);
#pragma unroll
      for (int dt = 0; dt < 4; ++dt) {
        int d = dt * 16 + r16;
        int cch = kb * 8 + c * 4 + g;
        s16x8 vb = *(const s16x8*)(vg + (size_t)d * 256 + cch * 8);
#pragma unroll
        for (int m = 0; m < 4; ++m) mfma16(accO[m][dt], pa[m], vb);
      }
    }
    asm volatile("s_waitcnt lgkmcnt(0)" ::: "memory");
    __builtin_amdgcn_sched_barrier(0);
  }

#pragma unroll
  for (int m = 0; m < 4; ++m)
#pragma unroll
    for (int dt = 0; dt < 4; ++dt)
#pragma unroll
      for (int r = 0; r < 4; ++r) {
        int rg = w * 256 + wv * 64 + m * 16 + g * 4 + r;
        int cg = h * 64 + dt * 16 + r16;
        float val = accO[m][dt][r] / Ls[m][r];
        attnout[(size_t)rg * 1024 + cg] = f2bf(val);
      }
}

// ---------------------------------------------------------------------------
extern "C" void kernel_launch(void* const* d_in, const int* in_sizes, int n_in,
                              void* d_out, int out_size, void* d_ws, size_t ws_size,
                              hipStream_t stream)
{
  const float* x    = (const float*)d_in[0];
  const float* c    = (const float*)d_in[1];
  const float* n1s  = (const float*)d_in[2];
  const float* n2s  = (const float*)d_in[3];
  const float* adaW = (const float*)d_in[4];
  const float* adaB = (const float*)d_in[5];
  const float* qkvW = (const float*)d_in[6];
  const float* qkvB = (const float*)d_in[7];
  const float* outW = (const float*)d_in[8];
  const float* outB = (const float*)d_in[9];
  const float* w12W = (const float*)d_in[10];
  const float* w12B = (const float*)d_in[11];
  const float* w3W  = (const float*)d_in[12];
  const float* w3B  = (const float*)d_in[13];

  char* ws = (char*)d_ws;
  constexpr size_t OFF_ADA  = 0;
  constexpr size_t OFF_QKVT = 98304;
  constexpr size_t OFF_OUTT = OFF_QKVT + 6291456;
  constexpr size_t OFF_W12T = OFF_OUTT + 2097152;
  constexpr size_t OFF_W3T  = OFF_W12T + 11534336;
  constexpr size_t OFF_BPAD = OFF_W3T + 5767168;
  constexpr size_t OFF_XM   = OFF_BPAD + 22528;
  constexpr size_t OFF_BIG  = OFF_XM + 33554432;       // = 59,365,376
  constexpr size_t OFF_QKVC = OFF_BIG;
  constexpr size_t OFF_VTC  = OFF_BIG + 50331648;
  constexpr size_t OFF_ATTC = OFF_BIG + 67108864;
  constexpr size_t OFF_HBUF = OFF_BIG;
  constexpr size_t OFF_QKVF = OFF_BIG;
  constexpr size_t OFF_VTF  = OFF_BIG + 100663296;
  constexpr size_t OFF_ATTF = OFF_BIG + 134217728;
  constexpr size_t NEED_FULL = OFF_BIG + 167772160;    // 227,137,536

  float* ada            = (float*)(ws + OFF_ADA);
  unsigned short* qkvT  = (unsigned short*)(ws + OFF_QKVT);
  unsigned short* outT  = (unsigned short*)(ws + OFF_OUTT);
  unsigned short* w12T  = (unsigned short*)(ws + OFF_W12T);
  unsigned short* w3T   = (unsigned short*)(ws + OFF_W3T);
  float* biasPad        = (float*)(ws + OFF_BPAD);
  unsigned short* xm    = (unsigned short*)(ws + OFF_XM);
  unsigned short* hbuf  = (unsigned short*)(ws + OFF_HBUF);
  float* x2             = (float*)d_out;

  // one setup dispatch: all transposes (pad-writing), biasPad, ada
  prep_all<<<12662, 256, 0, stream>>>(qkvW, qkvT, outW, outT, w12W, w12T,
                                      w3W, w3T, w12B, biasPad,
                                      c, adaW, adaB, ada);

  // --- attention branch ---
  rmsmod_kernel<<<4096, 256, 0, stream>>>(x, n1s, ada, 0, 1024, xm);
  if (ws_size >= NEED_FULL) {
    unsigned short* qkvF = (unsigned short*)(ws + OFF_QKVF);
    unsigned short* vTF  = (unsigned short*)(ws + OFF_VTF);
    unsigned short* attF = (unsigned short*)(ws + OFF_ATTF);
    gemm256<3><<<dim3(12, 64), 512, 0, stream>>>(
        xm, 1024, qkvT, 1024, 3072, 1024, qkvB, qkvF, 3072,
        nullptr, nullptr, 0, vTF);
    attn_kernel<<<1024, 256, 0, stream>>>(qkvF, vTF, attF);
    gemm256<2><<<dim3(4, 64), 512, 0, stream>>>(
        attF, 1024, outT, 1024, 1024, 1024, outB, x2, 1024,
        x, ada, 2048, nullptr);
  } else {
    unsigned short* qkvbC = (unsigned short*)(ws + OFF_QKVC);
    unsigned short* vTbC  = (unsigned short*)(ws + OFF_VTC);
    unsigned short* attnC = (unsigned short*)(ws + OFF_ATTC);
    for (int ch = 0; ch < 2; ++ch) {
      const size_t ro = (size_t)ch * 8192;
      gemm256<3><<<dim3(12, 32), 512, 0, stream>>>(
          xm + ro * 1024, 1024, qkvT, 1024, 3072, 1024, qkvB, qkvbC, 3072,
          nullptr, nullptr, 0, vTbC);
      attn_kernel<<<512, 256, 0, stream>>>(qkvbC, vTbC, attnC);
      gemm128<1><<<dim3(8, 64), 256, 0, stream>>>(
          attnC, 1024, outT, 1024, 1024, outB, x2 + ro * 1024, x + ro * 1024,
          ada, 2048, (int)ro);
    }
  }

  // --- MLP branch (full M = 16384) ---
  rmsmod_kernel<<<4096, 256, 0, stream>>>(x2, n2s, ada, 3072, 4096, xm);
  gemm256<1><<<dim3(22, 64), 512, 0, stream>>>(
      xm, 1024, w12T, 1024, 5632, 1024, biasPad, hbuf, 2816,
      nullptr, nullptr, 0, nullptr);
  gemm256<2><<<dim3(4, 64), 512, 0, stream>>>(
      hbuf, 2816, w3T, 2816, 1024, 2816, w3B, x2, 1024,
      x2, ada, 5120, nullptr);
}

// Round 16
// 681.174 us; speedup vs baseline: 1.0186x; 1.0186x over previous
//
#include <hip/hip_runtime.h>
#include <hip/hip_bf16.h>
#include <cstdint>
#include <cstddef>

#define DEV __device__ __forceinline__

typedef float f32x4 __attribute__((ext_vector_type(4)));
typedef short s16x8 __attribute__((ext_vector_type(8)));
typedef short s16x4 __attribute__((ext_vector_type(4)));
typedef __bf16 bf16x8 __attribute__((ext_vector_type(8)));

DEV unsigned short f2bf(float f) {
  union { float f; unsigned u; } v; v.f = f;
  return (unsigned short)((v.u + 0x7FFFu + ((v.u >> 16) & 1u)) >> 16);
}
DEV float bf2f(unsigned short s) {
  union { unsigned u; float f; } v; v.u = ((unsigned)s) << 16;
  return v.f;
}

DEV void mfma16(f32x4& d, const s16x8& a, const s16x8& b) {
  d = __builtin_amdgcn_mfma_f32_16x16x32_bf16(
      __builtin_bit_cast(bf16x8, a), __builtin_bit_cast(bf16x8, b), d, 0, 0, 0);
}

typedef const unsigned int gu32 __attribute__((address_space(1)));
typedef unsigned int lu32 __attribute__((address_space(3)));
DEV void gl_lds16(const void* g, void* l) {
  __builtin_amdgcn_global_load_lds((gu32*)g, (lu32*)l, 16, 0, 0);
}

// ---------------------------------------------------------------------------
// Zero-filling tile transpose: fp32 (Ksrc x nColsSrc submatrix) -> bf16.
// Reads outside the source range yield 0; writes are UNCONDITIONAL (caller
// guarantees the dst tile is in-range). ilv=1: dstRow = (n/16)*32+(n%16)+rowOff.
// ---------------------------------------------------------------------------
DEV void transpose_tile(const float* __restrict__ src, int srcLd, int Ksrc,
                        int colOff, int nColsSrc,
                        unsigned short* __restrict__ dst, int dstLd, int rowOff,
                        int ilv, int bx, int by, int tid)
{
  __shared__ float tile[32][33];
  int tx = tid & 31, ty = tid >> 5;
  int k0 = by * 32, n0 = bx * 32;
#pragma unroll
  for (int r = 0; r < 4; ++r) {
    int kk = k0 + ty + r * 8;
    int nn = n0 + tx;
    float v = 0.f;
    if (kk < Ksrc && nn < nColsSrc) v = src[(size_t)kk * srcLd + colOff + nn];
    tile[ty + r * 8][tx] = v;
  }
  __syncthreads();
#pragma unroll
  for (int r = 0; r < 4; ++r) {
    int nn = n0 + ty + r * 8;
    int kk = k0 + tx;
    int row = ilv ? (((nn >> 4) << 5) + (nn & 15) + rowOff) : (rowOff + nn);
    dst[(size_t)row * dstLd + kk] = f2bf(tile[tx][ty + r * 8]);
  }
}

// ---------------------------------------------------------------------------
// prep_all: 5 weight transposes (pad-writing, no memset needed) + w12 biasPad
// + ada GEMV, all in ONE dispatch (12662 blocks).
// ---------------------------------------------------------------------------
__global__ void prep_all(const float* __restrict__ qkvW, unsigned short* __restrict__ qkvT,
                         const float* __restrict__ outW, unsigned short* __restrict__ outT,
                         const float* __restrict__ w12W, unsigned short* __restrict__ w12T,
                         const float* __restrict__ w3W,  unsigned short* __restrict__ w3T,
                         const float* __restrict__ w12B, float* __restrict__ biasPad,
                         const float* __restrict__ c, const float* __restrict__ adaW,
                         const float* __restrict__ adaB, float* __restrict__ ada)
{
  const int id = blockIdx.x;
  const int tid = threadIdx.x;
  if (id < 3072) {
    transpose_tile(qkvW, 3072, 1024, 0, 3072, qkvT, 1024, 0, 0, id % 96, id / 96, tid);
  } else if (id < 4096) {
    int t = id - 3072;
    transpose_tile(outW, 1024, 1024, 0, 1024, outT, 1024, 0, 0, t % 32, t / 32, tid);
  } else if (id < 6912) {
    int t = id - 4096;
    transpose_tile(w12W, 5460, 1024, 0, 2730, w12T, 1024, 0, 1, t % 88, t / 88, tid);
  } else if (id < 9728) {
    int t = id - 6912;
    transpose_tile(w12W, 5460, 1024, 2730, 2730, w12T, 1024, 16, 1, t % 88, t / 88, tid);
  } else if (id < 12544) {
    int t = id - 9728;
    transpose_tile(w3W, 1024, 2730, 0, 1024, w3T, 2816, 0, 0, t % 32, t / 32, tid);
  } else if (id < 12566) {
    int n = (id - 12544) * 256 + tid;
    if (n < 5632) {
      int bb = n >> 4, i = n & 15;
      int src = ((bb >> 1) << 4) + i;
      float v = 0.f;
      if (src < 2730) v = (bb & 1) ? w12B[2730 + src] : w12B[src];
      biasPad[n] = v;
    }
  } else {
    __shared__ float cs[1024];
    int t = id - 12566;
    int bb = t / 24;
    int j = (t % 24) * 256 + tid;
    for (int i = tid; i < 1024; i += 256) {
      float v = c[bb * 1024 + i];
      cs[i] = v / (1.f + __expf(-v));
    }
    __syncthreads();
    float acc = adaB[j];
    for (int k = 0; k < 1024; ++k) acc = fmaf(cs[k], adaW[(size_t)k * 6144 + j], acc);
    ada[bb * 6144 + j] = acc;
  }
}

// ---------------------------------------------------------------------------
// rmsmod: wave-per-row (64 lanes x 16 f32), 4 rows/block, no LDS.
// ---------------------------------------------------------------------------
__global__ void rmsmod_kernel(const float* __restrict__ x, const float* __restrict__ nsc,
                              const float* __restrict__ ada, int shOff, int scOff,
                              unsigned short* __restrict__ out)
{
  const int lane = threadIdx.x & 63;
  const int wv = threadIdx.x >> 6;
  const int row = blockIdx.x * 4 + wv;
  const f32x4* xr = (const f32x4*)(x + (size_t)row * 1024);
  f32x4 v[4];
  float ss = 0.f;
#pragma unroll
  for (int c = 0; c < 4; ++c) {
    v[c] = xr[c * 64 + lane];
    ss += v[c][0]*v[c][0] + v[c][1]*v[c][1] + v[c][2]*v[c][2] + v[c][3]*v[c][3];
  }
#pragma unroll
  for (int off = 32; off >= 1; off >>= 1) ss += __shfl_xor(ss, off, 64);
  const float rms = rsqrtf(ss * (1.f / 1024.f) + 1e-6f);
  const int bb = row >> 12;
  const float* ab = ada + bb * 6144;
#pragma unroll
  for (int c = 0; c < 4; ++c) {
    s16x4 o;
#pragma unroll
    for (int i = 0; i < 4; ++i) {
      int col = (c * 64 + lane) * 4 + i;
      float xn = v[c][i] * rms * nsc[col];
      float val = xn * (1.f + ab[scOff + col]) + ab[shOff + col];
      o[i] = (short)f2bf(val);
    }
    *(s16x4*)(out + (size_t)row * 1024 + (c * 64 + lane) * 4) = o;
  }
}

// ---------------------------------------------------------------------------
// gemm256: C = A(bf16 MxK, lda) * BT(bf16 NxK, ldb)^T + bias.
// 256x256 tile, BK=64, 8 waves (2Mx4N), mfma_16x16x32. R5 2-barrier K-loop.
// EPI 1: silu-pair (16-interleaved w12) -> Nout=N/2
// EPI 2: f32 res + gate*(v+b)   (full-M only: gate row = rg>>12)
// EPI 3: qkv with fused V-transpose (cols>=2048 scatter to vT layout)
// Requires M%256==0, N%256==0, K%64==0, K/64>=2, grid%8==0.
// ---------------------------------------------------------------------------
template<int EPI>
__global__ __launch_bounds__(512, 2) void gemm256(
    const unsigned short* __restrict__ A, int lda,
    const unsigned short* __restrict__ BT, int ldb,
    int N, int K,
    const float* __restrict__ bias,
    void* __restrict__ Cout, int Nout,
    const float* __restrict__ res,
    const float* __restrict__ ada, int gateOff,
    unsigned short* __restrict__ vTout)
{
  __shared__ __align__(16) char lds[131072];

  const int tid = threadIdx.x;
  const int lane = tid & 63;
  const int wv = tid >> 6;
  const int wr = wv >> 2;        // 0..1  (M half)
  const int wn = wv & 3;         // 0..3  (N quarter)
  const int g = lane >> 4, r16 = lane & 15;

  // XCD-aware bijective block swizzle (grid % 8 == 0)
  const int nwg = gridDim.x * gridDim.y;
  const int bid = blockIdx.x + gridDim.x * blockIdx.y;
  const int qq = nwg >> 3;
  const int swz = (bid & 7) * qq + (bid >> 3);
  const int m0 = (swz / gridDim.x) * 256;
  const int n0 = (swz % gridDim.x) * 256;

  const int nkt = K >> 6;

  auto stageB = [&](int t) {
    if (t >= nkt) return;
    const int bs = t & 1;
#pragma unroll
    for (int it = 0; it < 4; ++it) {
      const int cidx = it * 512 + tid;
      const int rl = cidx >> 3, cc = cidx & 7;
      const unsigned short* src =
          BT + (size_t)(n0 + rl) * ldb + t * 64 + ((cc ^ (rl & 7)) << 3);
      gl_lds16(src, lds + 65536 + bs * 32768 + cidx * 16);
    }
  };
  auto stageA = [&](int t) {
    if (t >= nkt) return;
    const int bs = t & 1;
#pragma unroll
    for (int it = 0; it < 4; ++it) {
      const int cidx = it * 512 + tid;
      const int rl = cidx >> 3, cc = cidx & 7;
      const unsigned short* src =
          A + (size_t)(m0 + rl) * lda + t * 64 + ((cc ^ (rl & 7)) << 3);
      gl_lds16(src, lds + bs * 32768 + cidx * 16);
    }
  };

  f32x4 acc[8][4];
#pragma unroll
  for (int m = 0; m < 8; ++m)
#pragma unroll
    for (int n = 0; n < 4; ++n) { acc[m][n][0]=0.f; acc[m][n][1]=0.f; acc[m][n][2]=0.f; acc[m][n][3]=0.f; }

  int swzk[2];
#pragma unroll
  for (int ks = 0; ks < 2; ++ks) swzk[ks] = (((ks << 2) + g) ^ (r16 & 7)) << 4;
  int arow0[4], arow1[4], brow0[2], brow1[2];
#pragma unroll
  for (int m = 0; m < 4; ++m) {
    arow0[m] = (wr * 128 + m * 16 + r16) * 128;
    arow1[m] = (wr * 128 + 64 + m * 16 + r16) * 128;
  }
#pragma unroll
  for (int n = 0; n < 2; ++n) {
    brow0[n] = 65536 + (wn * 64 + n * 16 + r16) * 128;
    brow1[n] = 65536 + (wn * 64 + 32 + n * 16 + r16) * 128;
  }

  // prologue: tiles 0,1 staged; vmcnt(8) -> tile 0 landed
  stageB(0); stageA(0); stageB(1); stageA(1);
  asm volatile("s_waitcnt vmcnt(8)" ::: "memory");
  __builtin_amdgcn_s_barrier();

  for (int kt = 0; kt < nkt; ++kt) {
    const int boff = (kt & 1) * 32768;
    s16x8 a0[4][2], a1[4][2], b0[2][2], b1[2][2];
#pragma unroll
    for (int m = 0; m < 4; ++m)
#pragma unroll
      for (int ks = 0; ks < 2; ++ks)
        a0[m][ks] = *(const s16x8*)(lds + boff + arow0[m] + swzk[ks]);
#pragma unroll
    for (int n = 0; n < 2; ++n)
#pragma unroll
      for (int ks = 0; ks < 2; ++ks)
        b0[n][ks] = *(const s16x8*)(lds + boff + brow0[n] + swzk[ks]);
#pragma unroll
    for (int n = 0; n < 2; ++n)
#pragma unroll
      for (int ks = 0; ks < 2; ++ks)
        b1[n][ks] = *(const s16x8*)(lds + boff + brow1[n] + swzk[ks]);
#pragma unroll
    for (int m = 0; m < 4; ++m)
#pragma unroll
      for (int ks = 0; ks < 2; ++ks)
        a1[m][ks] = *(const s16x8*)(lds + boff + arow1[m] + swzk[ks]);
    // ---- Q00 ----
    __builtin_amdgcn_s_setprio(1);
#pragma unroll
    for (int m = 0; m < 4; ++m)
#pragma unroll
      for (int n = 0; n < 2; ++n)
#pragma unroll
        for (int ks = 0; ks < 2; ++ks)
          mfma16(acc[m][n], a0[m][ks], b0[n][ks]);
    __builtin_amdgcn_s_setprio(0);
    // ---- Q01 ----
    __builtin_amdgcn_s_setprio(1);
#pragma unroll
    for (int m = 0; m < 4; ++m)
#pragma unroll
      for (int n = 0; n < 2; ++n)
#pragma unroll
        for (int ks = 0; ks < 2; ++ks)
          mfma16(acc[m][2 + n], a0[m][ks], b1[n][ks]);
    __builtin_amdgcn_s_setprio(0);
    __builtin_amdgcn_s_barrier();          // BAR-mid: all B/a0 reads drained
    // ---- stage B(kt+2), Q11 ----
    stageB(kt + 2);
    __builtin_amdgcn_s_setprio(1);
#pragma unroll
    for (int m = 0; m < 4; ++m)
#pragma unroll
      for (int n = 0; n < 2; ++n)
#pragma unroll
        for (int ks = 0; ks < 2; ++ks)
          mfma16(acc[4 + m][2 + n], a1[m][ks], b1[n][ks]);
    __builtin_amdgcn_s_setprio(0);
    if (kt + 2 < nkt) asm volatile("s_waitcnt vmcnt(4)" ::: "memory");
    else              asm volatile("s_waitcnt vmcnt(0)" ::: "memory");
    __builtin_amdgcn_s_barrier();          // BAR-late: A drained + kt+1 landed
    // ---- stage A(kt+2), Q10 ----
    stageA(kt + 2);
    __builtin_amdgcn_s_setprio(1);
#pragma unroll
    for (int m = 0; m < 4; ++m)
#pragma unroll
      for (int n = 0; n < 2; ++n)
#pragma unroll
        for (int ks = 0; ks < 2; ++ks)
          mfma16(acc[4 + m][n], a1[m][ks], b0[n][ks]);
    __builtin_amdgcn_s_setprio(0);
  }

  if (EPI == 1) {
    unsigned short* Co = (unsigned short*)Cout;
#pragma unroll
    for (int fm = 0; fm < 8; ++fm)
#pragma unroll
      for (int p = 0; p < 2; ++p)
#pragma unroll
        for (int r = 0; r < 4; ++r) {
          int rg = m0 + wr * 128 + fm * 16 + g * 4 + r;
          int cg = n0 + wn * 64 + (2 * p) * 16 + r16;
          float v1 = acc[fm][2 * p][r] + bias[cg];
          float v2 = acc[fm][2 * p + 1][r] + bias[cg + 16];
          float h = v1 / (1.f + __expf(-v1)) * v2;
          int hcol = (n0 >> 1) + wn * 32 + p * 16 + r16;
          Co[(size_t)rg * Nout + hcol] = f2bf(h);
        }
  } else if (EPI == 2) {
    float* Co = (float*)Cout;
#pragma unroll
    for (int fm = 0; fm < 8; ++fm)
#pragma unroll
      for (int fn = 0; fn < 4; ++fn)
#pragma unroll
        for (int r = 0; r < 4; ++r) {
          int rg = m0 + wr * 128 + fm * 16 + g * 4 + r;
          int cg = n0 + wn * 64 + fn * 16 + r16;
          float v = acc[fm][fn][r] + bias[cg];
          int bb = rg >> 12;
          float gate = ada[bb * 6144 + gateOff + cg];
          size_t idx = (size_t)rg * Nout + cg;
          Co[idx] = res[idx] + gate * v;
        }
  } else { // EPI == 3: qkv; V-part (cols>=2048) scattered into vT layout
    unsigned short* Co = (unsigned short*)Cout;
#pragma unroll
    for (int fn = 0; fn < 4; ++fn) {
      int cg = n0 + wn * 64 + fn * 16 + r16;
      float bs = bias[cg];
      if (n0 + wn * 64 + fn * 16 < 2048) {
#pragma unroll
        for (int fm = 0; fm < 8; ++fm)
#pragma unroll
          for (int r = 0; r < 4; ++r) {
            int rg = m0 + wr * 128 + fm * 16 + g * 4 + r;
            Co[(size_t)rg * Nout + cg] = f2bf(acc[fm][fn][r] + bs);
          }
      } else {
        int h = (cg - 2048) >> 6, d = (cg - 2048) & 63;
        unsigned short* vcol = vTout + (size_t)h * 16384 + d * 256;
#pragma unroll
        for (int fm = 0; fm < 8; ++fm)
#pragma unroll
          for (int r = 0; r < 4; ++r) {
            int rg = m0 + wr * 128 + fm * 16 + g * 4 + r;
            vcol[((size_t)(rg >> 8) * 16) * 16384 + (rg & 255)] =
                f2bf(acc[fm][fn][r] + bs);
          }
      }
    }
  }
}

// ---------------------------------------------------------------------------
// GEMM 128x128 (2-barrier structure) for the chunked-fallback out-proj.
// ---------------------------------------------------------------------------
template<int MODE>
__global__ void gemm128(const unsigned short* __restrict__ A, int lda,
                        const unsigned short* __restrict__ BT,
                        int N, int K,
                        const float* __restrict__ bias,
                        void* __restrict__ Cout,
                        const float* __restrict__ res,
                        const float* __restrict__ ada, int gateOff, int mOff)
{
  __shared__ __align__(16) unsigned short As[128 * 32];
  __shared__ __align__(16) unsigned short Bs[128 * 32];

  const int tid = threadIdx.x;
  const int lane = tid & 63;
  const int wv = tid >> 6;
  const int wr = wv >> 1, wc = wv & 1;
  const int g = lane >> 4, r16 = lane & 15;
  const int m0 = blockIdx.y * 128, n0 = blockIdx.x * 128;

  const int c0 = tid, c1 = 256 + tid;
  const int ra0 = c0 >> 2, ra1 = c1 >> 2;
  const int k0 = ((c0 & 3) ^ ((ra0 >> 1) & 3)) * 8;
  const int k1 = ((c1 & 3) ^ ((ra1 >> 1) & 3)) * 8;
  const unsigned short* ga0 = A + (size_t)(m0 + ra0) * lda + k0;
  const unsigned short* ga1 = A + (size_t)(m0 + ra1) * lda + k1;
  const unsigned short* gb0 = BT + (size_t)(n0 + ra0) * K + k0;
  const unsigned short* gb1 = BT + (size_t)(n0 + ra1) * K + k1;
  unsigned short* la0 = As + c0 * 8;
  unsigned short* la1 = As + c1 * 8;
  unsigned short* lb0 = Bs + c0 * 8;
  unsigned short* lb1 = Bs + c1 * 8;

  f32x4 acc[4][4];
#pragma unroll
  for (int m = 0; m < 4; ++m)
#pragma unroll
    for (int n = 0; n < 4; ++n) { acc[m][n][0]=0.f; acc[m][n][1]=0.f; acc[m][n][2]=0.f; acc[m][n][3]=0.f; }

  int aoff[4], boff[4];
#pragma unroll
  for (int m = 0; m < 4; ++m) {
    int rl = wr * 64 + m * 16 + r16;
    aoff[m] = rl * 32 + (g ^ ((rl >> 1) & 3)) * 8;
    int rb = wc * 64 + m * 16 + r16;
    boff[m] = rb * 32 + (g ^ ((rb >> 1) & 3)) * 8;
  }

  const int nk = K >> 5;
  for (int kt = 0; kt < nk; ++kt) {
    __syncthreads();
    const int ko = kt * 32;
    gl_lds16(ga0 + ko, la0);
    gl_lds16(ga1 + ko, la1);
    gl_lds16(gb0 + ko, lb0);
    gl_lds16(gb1 + ko, lb1);
    __syncthreads();
    s16x8 af[4], bf[4];
#pragma unroll
    for (int m = 0; m < 4; ++m) af[m] = *(const s16x8*)(As + aoff[m]);
#pragma unroll
    for (int n = 0; n < 4; ++n) bf[n] = *(const s16x8*)(Bs + boff[n]);
#pragma unroll
    for (int m = 0; m < 4; ++m)
#pragma unroll
      for (int n = 0; n < 4; ++n) mfma16(acc[m][n], af[m], bf[n]);
  }

#pragma unroll
  for (int m = 0; m < 4; ++m) {
#pragma unroll
    for (int n = 0; n < 4; ++n) {
#pragma unroll
      for (int r = 0; r < 4; ++r) {
        int rg = m0 + wr * 64 + m * 16 + g * 4 + r;
        int cg = n0 + wc * 64 + n * 16 + r16;
        float v = acc[m][n][r] + bias[cg];
        size_t idx = (size_t)rg * N + cg;
        if (MODE == 0 || MODE == 2) {
          ((unsigned short*)Cout)[idx] = f2bf(v);
        } else {
          int bb = (mOff + rg) >> 12;
          float gate = ada[bb * 6144 + gateOff + cg];
          ((float*)Cout)[idx] = res[idx] + gate * v;
        }
      }
    }
  }
}

// ---------------------------------------------------------------------------
// Fused windowed attention, one block per (window, head). 4 waves x 64 q-rows.
// K and V staged in LDS (XOR-swizzled); P through per-wave LDS.
// ---------------------------------------------------------------------------
__global__ __launch_bounds__(256, 1) void attn_kernel(
    const unsigned short* __restrict__ qkv,
    const unsigned short* __restrict__ vT,
    unsigned short* __restrict__ attnout)
{
  __shared__ __align__(16) unsigned short Kl[256 * 64];
  __shared__ __align__(16) unsigned short Vl[64 * 256];
  __shared__ __align__(16) unsigned short Pl[4][64 * 88];

  const int tid = threadIdx.x;
  const int lane = tid & 63;
  const int wv = tid >> 6;
  const int g = lane >> 4, r16 = lane & 15;
  const int p = blockIdx.x;
  const int w = p >> 4, h = p & 15;
  const float hh = (float)h;
  const float F = 0.4152410118609203f; // log2(10000)/32

#pragma unroll
  for (int it = 0; it < 4; ++it) {
    int idx = it * 256 + tid;
    int j = idx >> 2;
    int c = idx & 3;
    const unsigned short* kg = qkv + (size_t)(w * 256 + j) * 3072 + 1024 + h * 64;
    s16x8 lo = *(const s16x8*)(kg + c * 8);
    s16x8 hi = *(const s16x8*)(kg + 32 + c * 8);
    s16x8 plo, phi;
#pragma unroll
    for (int i2 = 0; i2 < 4; ++i2) {
      float f1 = exp2f(-(float)(c * 4 + i2) * F);
      float f2 = exp2f(-(float)(16 + c * 4 + i2) * F);
      float s1, c1s, s2, c2s;
      sincosf(hh * f1, &s1, &c1s);
      sincosf(hh * f2, &s2, &c2s);
#pragma unroll
      for (int u = 0; u < 2; ++u) {
        int i = i2 * 2 + u;
        float a = bf2f((unsigned short)lo[i]);
        float b = bf2f((unsigned short)hi[i]);
        plo[i] = (short)f2bf(a * c1s - b * s1);
        phi[i] = (short)f2bf(b * c2s + a * s2);
      }
    }
    int swzL = c ^ (j & 7);
    int swzH = (c + 4) ^ (j & 7);
    *(s16x8*)(Kl + j * 64 + swzL * 8) = plo;
    *(s16x8*)(Kl + j * 64 + swzH * 8) = phi;
  }
  {
    const unsigned short* vg = vT + (size_t)p * (64 * 256);
#pragma unroll
    for (int it = 0; it < 8; ++it) {
      int idx = it * 256 + tid;
      int d = idx >> 5;
      int c = idx & 31;
      s16x8 val = *(const s16x8*)(vg + d * 256 + c * 8);
      int cs = (c & ~7) | ((c ^ d) & 7);
      *(s16x8*)(Vl + d * 256 + cs * 8) = val;
    }
  }

  s16x8 qa[4][2];
  {
    float cs0[4], sn0[4], cs1[4], sn1[4];
#pragma unroll
    for (int i2 = 0; i2 < 4; ++i2) {
      float f1 = exp2f(-(float)(g * 4 + i2) * F);
      float f2 = exp2f(-(float)(16 + g * 4 + i2) * F);
      sincosf(hh * f1, &sn0[i2], &cs0[i2]);
      sincosf(hh * f2, &sn1[i2], &cs1[i2]);
    }
#pragma unroll
    for (int m = 0; m < 4; ++m) {
      const unsigned short* qg =
          qkv + (size_t)(w * 256 + wv * 64 + m * 16 + r16) * 3072 + h * 64;
      s16x8 lo = *(const s16x8*)(qg + g * 8);
      s16x8 hi = *(const s16x8*)(qg + 32 + g * 8);
      s16x8 plo, phi;
#pragma unroll
      for (int i = 0; i < 8; ++i) {
        int i2 = i >> 1;
        float a = bf2f((unsigned short)lo[i]);
        float b = bf2f((unsigned short)hi[i]);
        plo[i] = (short)f2bf(a * cs0[i2] - b * sn0[i2]);
        phi[i] = (short)f2bf(b * cs1[i2] + a * sn1[i2]);
      }
      qa[m][0] = plo;
      qa[m][1] = phi;
    }
  }

  __syncthreads();

  f32x4 accO[4][4];
  float Mx[4][4], Ls[4][4];
#pragma unroll
  for (int m = 0; m < 4; ++m)
#pragma unroll
    for (int r = 0; r < 4; ++r) {
      Mx[m][r] = -3.0e38f;
      Ls[m][r] = 0.f;
      accO[m][r][0]=0.f; accO[m][r][1]=0.f; accO[m][r][2]=0.f; accO[m][r][3]=0.f;
    }
  unsigned short* Pw = &Pl[wv][0];
  const float zs = 0.125f * 1.44269504f;

  for (int kb = 0; kb < 4; ++kb) {
    f32x4 s[4][4];
#pragma unroll
    for (int m = 0; m < 4; ++m)
#pragma unroll
      for (int jt = 0; jt < 4; ++jt) { s[m][jt][0]=0.f; s[m][jt][1]=0.f; s[m][jt][2]=0.f; s[m][jt][3]=0.f; }

#pragma unroll
    for (int jt = 0; jt < 4; ++jt) {
      int j = kb * 64 + jt * 16 + r16;
      s16x8 bk0 = *(const s16x8*)(Kl + j * 64 + ((g ^ (j & 7)) * 8));
      s16x8 bk1 = *(const s16x8*)(Kl + j * 64 + (((4 + g) ^ (j & 7)) * 8));
#pragma unroll
      for (int m = 0; m < 4; ++m) {
        mfma16(s[m][jt], qa[m][0], bk0);
        mfma16(s[m][jt], qa[m][1], bk1);
      }
    }

#pragma unroll
    for (int m = 0; m < 4; ++m) {
#pragma unroll
      for (int r = 0; r < 4; ++r) {
        float mx = fmaxf(fmaxf(s[m][0][r], s[m][1][r]), fmaxf(s[m][2][r], s[m][3][r]));
        mx = fmaxf(mx, __shfl_xor(mx, 1, 16));
        mx = fmaxf(mx, __shfl_xor(mx, 2, 16));
        mx = fmaxf(mx, __shfl_xor(mx, 4, 16));
        mx = fmaxf(mx, __shfl_xor(mx, 8, 16));
        float Mn = fmaxf(Mx[m][r], mx * zs);
        float fsc = exp2f(Mx[m][r] - Mn);
        Mx[m][r] = Mn;
        float ps = 0.f;
#pragma unroll
        for (int jt = 0; jt < 4; ++jt) {
          float pv = exp2f(s[m][jt][r] * zs - Mn);
          s[m][jt][r] = pv;
          ps += pv;
        }
        ps += __shfl_xor(ps, 1, 16);
        ps += __shfl_xor(ps, 2, 16);
        ps += __shfl_xor(ps, 4, 16);
        ps += __shfl_xor(ps, 8, 16);
        Ls[m][r] = Ls[m][r] * fsc + ps;
#pragma unroll
        for (int dt = 0; dt < 4; ++dt) accO[m][dt][r] *= fsc;
      }
    }

#pragma unroll
    for (int m = 0; m < 4; ++m)
#pragma unroll
      for (int jt = 0; jt < 4; ++jt)
#pragma unroll
        for (int r = 0; r < 4; ++r) {
          int q = m * 16 + g * 4 + r;
          int jj = jt * 16 + r16;
          Pw[q * 88 + jj] = f2bf(s[m][jt][r]);
        }
    asm volatile("s_waitcnt lgkmcnt(0)" ::: "memory");
    __builtin_amdgcn_sched_barrier(0);

#pragma unroll
    for (int c = 0; c < 2; ++c) {
      s16x8 pa[4];
#pragma unroll
      for (int m = 0; m < 4; ++m)
        pa[m] = *(const s16x8*)(Pw + (m * 16 + r16) * 88 + c * 32 + g * 8);
#pragma unroll
      for (int dt = 0; dt < 4; ++dt) {
        int d = dt * 16 + r16;
        int cch = kb * 8 + c * 4 + g;
        int csz = (cch & ~7) | ((cch ^ d) & 7);
        s16x8 vb = *(const s16x8*)(Vl + d * 256 + csz * 8);
#pragma unroll
        for (int m = 0; m < 4; ++m) mfma16(accO[m][dt], pa[m], vb);
      }
    }
    asm volatile("s_waitcnt lgkmcnt(0)" ::: "memory");
    __builtin_amdgcn_sched_barrier(0);
  }

#pragma unroll
  for (int m = 0; m < 4; ++m)
#pragma unroll
    for (int dt = 0; dt < 4; ++dt)
#pragma unroll
      for (int r = 0; r < 4; ++r) {
        int rg = w * 256 + wv * 64 + m * 16 + g * 4 + r;
        int cg = h * 64 + dt * 16 + r16;
        float val = accO[m][dt][r] / Ls[m][r];
        attnout[(size_t)rg * 1024 + cg] = f2bf(val);
      }
}

// ---------------------------------------------------------------------------
extern "C" void kernel_launch(void* const* d_in, const int* in_sizes, int n_in,
                              void* d_out, int out_size, void* d_ws, size_t ws_size,
                              hipStream_t stream)
{
  const float* x    = (const float*)d_in[0];
  const float* c    = (const float*)d_in[1];
  const float* n1s  = (const float*)d_in[2];
  const float* n2s  = (const float*)d_in[3];
  const float* adaW = (const float*)d_in[4];
  const float* adaB = (const float*)d_in[5];
  const float* qkvW = (const float*)d_in[6];
  const float* qkvB = (const float*)d_in[7];
  const float* outW = (const float*)d_in[8];
  const float* outB = (const float*)d_in[9];
  const float* w12W = (const float*)d_in[10];
  const float* w12B = (const float*)d_in[11];
  const float* w3W  = (const float*)d_in[12];
  const float* w3B  = (const float*)d_in[13];

  char* ws = (char*)d_ws;
  constexpr size_t OFF_ADA  = 0;
  constexpr size_t OFF_QKVT = 98304;
  constexpr size_t OFF_OUTT = OFF_QKVT + 6291456;
  constexpr size_t OFF_W12T = OFF_OUTT + 2097152;
  constexpr size_t OFF_W3T  = OFF_W12T + 11534336;
  constexpr size_t OFF_BPAD = OFF_W3T + 5767168;
  constexpr size_t OFF_XM   = OFF_BPAD + 22528;
  constexpr size_t OFF_BIG  = OFF_XM + 33554432;       // = 59,365,376
  constexpr size_t OFF_QKVC = OFF_BIG;
  constexpr size_t OFF_VTC  = OFF_BIG + 50331648;
  constexpr size_t OFF_ATTC = OFF_BIG + 67108864;
  constexpr size_t OFF_HBUF = OFF_BIG;
  constexpr size_t OFF_QKVF = OFF_BIG;
  constexpr size_t OFF_VTF  = OFF_BIG + 100663296;
  constexpr size_t OFF_ATTF = OFF_BIG + 134217728;
  constexpr size_t NEED_FULL = OFF_BIG + 167772160;    // 227,137,536

  float* ada            = (float*)(ws + OFF_ADA);
  unsigned short* qkvT  = (unsigned short*)(ws + OFF_QKVT);
  unsigned short* outT  = (unsigned short*)(ws + OFF_OUTT);
  unsigned short* w12T  = (unsigned short*)(ws + OFF_W12T);
  unsigned short* w3T   = (unsigned short*)(ws + OFF_W3T);
  float* biasPad        = (float*)(ws + OFF_BPAD);
  unsigned short* xm    = (unsigned short*)(ws + OFF_XM);
  unsigned short* hbuf  = (unsigned short*)(ws + OFF_HBUF);
  float* x2             = (float*)d_out;

  // one setup dispatch: all transposes (pad-writing), biasPad, ada
  prep_all<<<12662, 256, 0, stream>>>(qkvW, qkvT, outW, outT, w12W, w12T,
                                      w3W, w3T, w12B, biasPad,
                                      c, adaW, adaB, ada);

  // --- attention branch ---
  rmsmod_kernel<<<4096, 256, 0, stream>>>(x, n1s, ada, 0, 1024, xm);
  if (ws_size >= NEED_FULL) {
    unsigned short* qkvF = (unsigned short*)(ws + OFF_QKVF);
    unsigned short* vTF  = (unsigned short*)(ws + OFF_VTF);
    unsigned short* attF = (unsigned short*)(ws + OFF_ATTF);
    gemm256<3><<<dim3(12, 64), 512, 0, stream>>>(
        xm, 1024, qkvT, 1024, 3072, 1024, qkvB, qkvF, 3072,
        nullptr, nullptr, 0, vTF);
    attn_kernel<<<1024, 256, 0, stream>>>(qkvF, vTF, attF);
    gemm256<2><<<dim3(4, 64), 512, 0, stream>>>(
        attF, 1024, outT, 1024, 1024, 1024, outB, x2, 1024,
        x, ada, 2048, nullptr);
  } else {
    unsigned short* qkvbC = (unsigned short*)(ws + OFF_QKVC);
    unsigned short* vTbC  = (unsigned short*)(ws + OFF_VTC);
    unsigned short* attnC = (unsigned short*)(ws + OFF_ATTC);
    for (int ch = 0; ch < 2; ++ch) {
      const size_t ro = (size_t)ch * 8192;
      gemm256<3><<<dim3(12, 32), 512, 0, stream>>>(
          xm + ro * 1024, 1024, qkvT, 1024, 3072, 1024, qkvB, qkvbC, 3072,
          nullptr, nullptr, 0, vTbC);
      attn_kernel<<<512, 256, 0, stream>>>(qkvbC, vTbC, attnC);
      gemm128<1><<<dim3(8, 64), 256, 0, stream>>>(
          attnC, 1024, outT, 1024, 1024, outB, x2 + ro * 1024, x + ro * 1024,
          ada, 2048, (int)ro);
    }
  }

  // --- MLP branch (full M = 16384) ---
  rmsmod_kernel<<<4096, 256, 0, stream>>>(x2, n2s, ada, 3072, 4096, xm);
  gemm256<1><<<dim3(22, 64), 512, 0, stream>>>(
      xm, 1024, w12T, 1024, 5632, 1024, biasPad, hbuf, 2816,
      nullptr, nullptr, 0, nullptr);
  gemm256<2><<<dim3(4, 64), 512, 0, stream>>>(
      hbuf, 2816, w3T, 2816, 1024, 2816, w3B, x2, 1024,
      x2, ada, 5120, nullptr);
}